// Round 12
// baseline (5750.234 us; speedup 1.0000x reference)
//
#include <hip/hip_runtime.h>

#define Tc 100
#define Hc 512
#define Lc 3
#define H3c 1536
#define HLAY (Hc*Hc)            // elems per layer slice of an hb parity slot
#define HSLOT (Lc*HLAY)         // elems per parity slot

typedef short bf16x8 __attribute__((ext_vector_type(8)));
typedef float f32x4 __attribute__((ext_vector_type(4)));

__device__ __forceinline__ unsigned short f2bf(float f) {
  unsigned int u = __float_as_uint(f);
  u += 0x7FFFu + ((u >> 16) & 1u);   // round-to-nearest-even
  return (unsigned short)(u >> 16);
}

__global__ __launch_bounds__(256) void conv_bf16(const float* __restrict__ src,
                                                 unsigned short* __restrict__ dst,
                                                 int n4) {
  int i = blockIdx.x * 256 + threadIdx.x;
  if (i >= n4) return;
  f32x4 v = *(const f32x4*)(src + (size_t)i * 4);
  ushort4 o;
  o.x = f2bf(v[0]); o.y = f2bf(v[1]); o.z = f2bf(v[2]); o.w = f2bf(v[3]);
  *(ushort4*)(dst + (size_t)i * 4) = o;
}

// Lane-parallel group wait on 16 monotonic per-producer counters (store-
// published, never RMW'd). sc0sc1 polls read the coherence point. Self-drains.
__device__ __forceinline__ void waitg(const int* slots, int tgt, int lane) {
  const int* p = slots + (lane & 15);
  int it = 0;
  for (;;) {
    int v;
    asm volatile("global_load_dword %0, %1, off sc0 sc1\n\ts_waitcnt vmcnt(0)"
                 : "=v"(v) : "v"(p) : "memory");
    if (__all(v >= tgt)) break;
    __builtin_amdgcn_s_sleep(1);
    if (++it > 4000000) break;      // deadlock bug -> fast fail, not hang
  }
}

#define LOADC(dst, ptr) \
  asm volatile("global_load_dwordx4 %0, %1, off sc0 sc1" : "=v"(dst) : "v"(ptr))
#define LOADN(dst, ptr) \
  asm volatile("global_load_dwordx4 %0, %1, off" : "=v"(dst) : "v"(ptr))
#define STORE_H2(ptr, v32) \
  asm volatile("global_store_short %0, %1, off sc0 sc1" :: "v"(ptr), "v"(v32))
#define STORE_D(ptr, v32) \
  asm volatile("global_store_dword %0, %1, off sc0 sc1" :: "v"(ptr), "v"(v32))
#define WAITV(n) do { asm volatile("s_waitcnt vmcnt(" #n ")" ::: "memory"); \
                      __builtin_amdgcn_sched_barrier(0); } while (0)
#define MM(a, b, c) c = __builtin_amdgcn_mfma_f32_16x16x32_bf16(a, b, c, 0, 0, 0)

// Persistent dataflow GRU, round-12 decomposition:
//   12 groups = 3 layers x 4 rowblocks(128 rows); 16 colblocks x 32 cols.
//   A+H per block per stage = 256 KB (HALF of r8's 512 KB -> 48 MB/stage
//   chip-wide, attacking the measured L3-path roofline).
//   Weights: NO LDS — streamed from L2 via normal cached loads (static data,
//   never stale). cb-colocated XCD map keeps per-XCD weight set at 1.2 MB.
//   Everything else = r8's proven structure: sc0sc1 h-ring (row-major),
//   counted-vmcnt depth-2 K-loop (16 uniform asm loads per ks), scattered
//   STORE_H2 epilogue, RMW-free done[12][16] flags, 3-wave parallel waits.
__global__ __launch_bounds__(256, 1) void gru_persist11(
    const float* __restrict__ x,     // [B,T,A,H] f32 (fallback)
    const short* __restrict__ xb,    // [B,T,A,H] bf16 or nullptr
    const short* __restrict__ wbih,  // [L,3H,H] bf16
    const short* __restrict__ wbhh,  // [L,3H,H] bf16
    const float* __restrict__ bih,   // [L,3H]
    const float* __restrict__ bhh,   // [L,3H]
    short* hb,                       // [2][L][512][512] bf16 parity ring
    const int* __restrict__ valid,   // [B,T,A] int32
    float* __restrict__ y,           // [B,T,A,H] f32
    int* done) {                     // [12][16] monotonic counters
  const int bid = blockIdx.x;
  const int xcd = bid & 7;
  const int q = bid >> 3;            // 0..23
  const int gi = q % 12;             // group = l*4+rb
  const int cb = xcd * 2 + q / 12;   // 0..15 — same-cb blocks share an XCD
  const int l = gi >> 2;
  const int rb = gi & 3;
  const int c0 = cb * 32;
  const int R0 = rb * 128;

  const int tid = threadIdx.x;
  const int w = tid >> 6;
  const int lane = tid & 63;
  const int lrow = lane & 15;
  const int kgrp = lane >> 4;
  const int koff = kgrp * 8;

  const short* wih_l = wbih + (size_t)l * H3c * Hc;
  const short* whh_l = wbhh + (size_t)l * H3c * Hc;

  // weight fragment base pointers (L2-streamed): B[n=gate*512+col][k]
  const short* pBi[3][2];
  const short* pBh[3][2];
#pragma unroll
  for (int g3 = 0; g3 < 3; ++g3)
#pragma unroll
    for (int cf = 0; cf < 2; ++cf) {
      int n = g3 * Hc + c0 + cf * 16 + lrow;
      pBi[g3][cf] = wih_l + (size_t)n * Hc + koff;
      pBh[g3][cf] = whh_l + (size_t)n * Hc + koff;
    }

  const float* bihl = bih + l * H3c;
  const float* bhhl = bhh + l * H3c;
  float bi_[3][2], bh_[3][2];
#pragma unroll
  for (int g3 = 0; g3 < 3; ++g3)
#pragma unroll
    for (int cf = 0; cf < 2; ++cf) {
      int c2 = c0 + cf * 16 + lrow;
      bi_[g3][cf] = bihl[g3 * Hc + c2];
      bh_[g3][cf] = bhhl[g3 * Hc + c2];
    }

  f32x4 hreg[2][2];
#pragma unroll
  for (int rf = 0; rf < 2; ++rf)
#pragma unroll
    for (int cf = 0; cf < 2; ++cf) hreg[rf][cf] = f32x4{0.f, 0.f, 0.f, 0.f};

  WAITV(0);                          // setup loads drained before counted regions

  for (int t = 0; t < Tc; ++t) {
    // parallel waits on 3 waves (coherence-point polls, no RMW anywhere)
    if (w == 0 && l > 0)           waitg(done + ((l - 1) * 4 + rb) * 16, t + 1, lane);
    if (w == 1 && t > 0)           waitg(done + gi * 16, t, lane);
    if (w == 2 && l < 2 && t >= 2) waitg(done + ((l + 1) * 4 + rb) * 16, t - 1, lane);
    __syncthreads();

    const int par = t & 1;
    const short* hprev = hb + (size_t)(1 - par) * HSLOT + (size_t)l * HLAY;

    const short* pH[2];
    const short* pA[2] = {nullptr, nullptr};
    const float* pXf[2] = {x, x};
#pragma unroll
    for (int rf = 0; rf < 2; ++rf) {
      int row = R0 + w * 32 + rf * 16 + lrow;
      pH[rf] = hprev + (size_t)row * Hc + koff;
      if (l > 0) {
        pA[rf] = hb + (size_t)par * HSLOT + (size_t)(l - 1) * HLAY + (size_t)row * Hc + koff;
      } else {
        int bb = row >> 6, aa = row & 63;
        size_t rofs = ((size_t)bb * Tc + t) * 64 + aa;
        if (xb) pA[rf] = xb + rofs * Hc + koff;
        pXf[rf] = x + rofs * Hc + koff;
      }
    }

    f32x4 acc[6][2][2];
#pragma unroll
    for (int m = 0; m < 6; ++m)
#pragma unroll
      for (int rf = 0; rf < 2; ++rf)
#pragma unroll
        for (int cf = 0; cf < 2; ++cf) acc[m][rf][cf] = f32x4{0.f, 0.f, 0.f, 0.f};

#define AI_C(A_, rf, ke) LOADC(A_[rf], pA[rf] + (ke))
#define AI_N(A_, rf, ke) LOADN(A_[rf], pA[rf] + (ke))
#define AI_X(A_, rf, ke)

    // 16 uniform asm loads per ks: 2 H(sc) + 2 A + 12 B(normal, L2-resident)
#define ISSUE(H_, A_, BI_, BH_, ks, AI_ISS)                                        \
      { const int ke = (ks) * 32;                                                  \
        _Pragma("unroll") for (int rf = 0; rf < 2; ++rf) {                         \
          LOADC(H_[rf], pH[rf] + ke);                                              \
          AI_ISS(A_, rf, ke);                                                      \
        }                                                                          \
        _Pragma("unroll") for (int g3 = 0; g3 < 3; ++g3)                           \
          _Pragma("unroll") for (int cf = 0; cf < 2; ++cf) {                       \
            LOADN(BI_[g3][cf], pBi[g3][cf] + ke);                                  \
            LOADN(BH_[g3][cf], pBh[g3][cf] + ke);                                  \
          } }

#define CONSUME(H_, A_, BI_, BH_)                                                  \
      { _Pragma("unroll") for (int g3 = 0; g3 < 3; ++g3)                           \
          _Pragma("unroll") for (int cf = 0; cf < 2; ++cf)                         \
            _Pragma("unroll") for (int rf = 0; rf < 2; ++rf) {                     \
              MM(A_[rf], BI_[g3][cf], acc[g3][rf][cf]);                            \
              MM(H_[rf], BH_[g3][cf], acc[3 + g3][rf][cf]);                        \
            } }

    __builtin_amdgcn_sched_barrier(0);
    if (l > 0 || xb) {
      bf16x8 Ha[2], Aa[2], Bia[3][2], Bha[3][2];
      bf16x8 Hb[2], Ab[2], Bib[3][2], Bhb[3][2];
      if (l > 0) { ISSUE(Ha, Aa, Bia, Bha, 0, AI_C) }
      else       { ISSUE(Ha, Aa, Bia, Bha, 0, AI_N) }
#pragma unroll
      for (int k2 = 0; k2 < 16; k2 += 2) {
        if (l > 0) { ISSUE(Hb, Ab, Bib, Bhb, k2 + 1, AI_C) }
        else       { ISSUE(Hb, Ab, Bib, Bhb, k2 + 1, AI_N) }
        WAITV(16);
        CONSUME(Ha, Aa, Bia, Bha);
        if (k2 + 2 < 16) {
          if (l > 0) { ISSUE(Ha, Aa, Bia, Bha, k2 + 2, AI_C) }
          else       { ISSUE(Ha, Aa, Bia, Bha, k2 + 2, AI_N) }
          WAITV(16);
        } else {
          WAITV(0);
        }
        CONSUME(Hb, Ab, Bib, Bhb);
      }
    } else {                         // fallback (no xb): single-buffered drains
      bf16x8 Ha[2], Aa[2], Bia[3][2], Bha[3][2];
#pragma unroll
      for (int ks = 0; ks < 16; ++ks) {
        ISSUE(Ha, Aa, Bia, Bha, ks, AI_X);
        WAITV(0);
#pragma unroll
        for (int rf = 0; rf < 2; ++rf) {
          f32x4 v0 = *(const f32x4*)(pXf[rf] + ks * 32);
          f32x4 v1 = *(const f32x4*)(pXf[rf] + ks * 32 + 4);
          bf16x8 t_;
#pragma unroll
          for (int e = 0; e < 4; ++e) {
            t_[e] = (short)f2bf(v0[e]); t_[4 + e] = (short)f2bf(v1[e]);
          }
          Aa[rf] = t_;
        }
        CONSUME(Ha, Aa, Bia, Bha);
      }
    }
    __builtin_amdgcn_sched_barrier(0);

    // epilogue (r8 proven form): C/D map col=lane&15, row=(lane>>4)*4+reg
    short* hout = hb + (size_t)par * HSLOT + (size_t)l * HLAY;
#pragma unroll
    for (int rf = 0; rf < 2; ++rf) {
#pragma unroll
      for (int rr = 0; rr < 4; ++rr) {
        int rowg = R0 + w * 32 + rf * 16 + kgrp * 4 + rr;
        int bb = rowg >> 6, aa = rowg & 63;
        size_t vofs = ((size_t)bb * Tc + t) * 64 + aa;
        int vld = valid[vofs];
#pragma unroll
        for (int cf = 0; cf < 2; ++cf) {
          int c = c0 + cf * 16 + lrow;
          float ir = acc[0][rf][cf][rr] + bi_[0][cf];
          float iz = acc[1][rf][cf][rr] + bi_[1][cf];
          float in_ = acc[2][rf][cf][rr] + bi_[2][cf];
          float hr = acc[3][rf][cf][rr] + bh_[0][cf];
          float hz = acc[4][rf][cf][rr] + bh_[1][cf];
          float hn = acc[5][rf][cf][rr] + bh_[2][cf];
          float rg = 1.0f / (1.0f + __expf(-(ir + hr)));
          float zg = 1.0f / (1.0f + __expf(-(iz + hz)));
          float ng = tanhf(in_ + rg * hn);
          float hnew = (1.0f - zg) * ng + zg * hreg[rf][cf][rr];
          if (!vld) hnew = 0.0f;
          hreg[rf][cf][rr] = hnew;
          int hv = (int)f2bf(hnew);
          STORE_H2(hout + (size_t)rowg * Hc + c, hv);
          if (l == 2) y[vofs * Hc + c] = hnew;
        }
      }
    }

    asm volatile("s_waitcnt vmcnt(0)" ::: "memory");   // sc stores + y drained
    __syncthreads();                                   // all waves' stores done
    if (tid == 0) {                  // publish: single sc STORE, no RMW
      int v = t + 1;
      STORE_D(done + gi * 16 + cb, v);
    }
    WAITV(0);   // drain publish store: vmcnt clean for next counted region
  }
}

extern "C" void kernel_launch(void* const* d_in, const int* in_sizes, int n_in,
                              void* d_out, int out_size, void* d_ws, size_t ws_size,
                              hipStream_t stream) {
  const float* x = (const float*)d_in[0];
  const int* valid = (const int*)d_in[1];
  const float* w_ih = (const float*)d_in[2];
  const float* w_hh = (const float*)d_in[3];
  const float* b_ih = (const float*)d_in[4];
  const float* b_hh = (const float*)d_in[5];
  float* y = (float*)d_out;

  char* ws = (char*)d_ws;
  const size_t welems = (size_t)Lc * H3c * Hc;            // 2,359,296
  unsigned short* wbih = (unsigned short*)ws;
  unsigned short* wbhh = (unsigned short*)(ws + welems * 2);
  short* hb = (short*)(ws + welems * 4);                  // 3.0 MB ring
  const size_t hb_bytes = (size_t)2 * HSLOT * 2;
  int* done = (int*)(ws + welems * 4 + hb_bytes);         // [12][16] = 768 B
  const size_t flags_bytes = 4800;
  const size_t xb_off = welems * 4 + hb_bytes + flags_bytes;  // 16B aligned
  const size_t xelems = (size_t)8 * Tc * 64 * Hc;         // 26,214,400
  const bool big = ws_size >= xb_off + xelems * 2;
  unsigned short* xbf = big ? (unsigned short*)(ws + xb_off) : nullptr;

  int n4w = (int)(welems / 4);
  conv_bf16<<<(n4w + 255) / 256, 256, 0, stream>>>(w_ih, wbih, n4w);
  conv_bf16<<<(n4w + 255) / 256, 256, 0, stream>>>(w_hh, wbhh, n4w);
  if (big) {
    int n4x = (int)(xelems / 4);
    conv_bf16<<<(n4x + 255) / 256, 256, 0, stream>>>(x, xbf, n4x);
  }
  (void)hipMemsetAsync(hb, 0, hb_bytes + flags_bytes, stream);

  gru_persist11<<<192, 256, 0, stream>>>(x, (const short*)xbf,
                                         (const short*)wbih, (const short*)wbhh,
                                         b_ih, b_hh, hb, valid, y, done);
}

// Round 13
// 2666.972 us; speedup vs baseline: 2.1561x; 2.1561x over previous
//
#include <hip/hip_runtime.h>

#define Tc 100
#define Hc 512
#define Lc 3
#define H3c 1536
#define HLAY (Hc*Hc)            // elems per layer slice of an hb parity slot
#define HSLOT (Lc*HLAY)         // elems per parity slot

typedef short bf16x8 __attribute__((ext_vector_type(8)));
typedef float f32x4 __attribute__((ext_vector_type(4)));

__device__ __forceinline__ unsigned short f2bf(float f) {
  unsigned int u = __float_as_uint(f);
  u += 0x7FFFu + ((u >> 16) & 1u);   // round-to-nearest-even
  return (unsigned short)(u >> 16);
}

__global__ __launch_bounds__(256) void conv_bf16(const float* __restrict__ src,
                                                 unsigned short* __restrict__ dst,
                                                 int n4) {
  int i = blockIdx.x * 256 + threadIdx.x;
  if (i >= n4) return;
  f32x4 v = *(const f32x4*)(src + (size_t)i * 4);
  ushort4 o;
  o.x = f2bf(v[0]); o.y = f2bf(v[1]); o.z = f2bf(v[2]); o.w = f2bf(v[3]);
  *(ushort4*)(dst + (size_t)i * 4) = o;
}

// Lane-parallel group wait on 32 monotonic per-producer counters (store-
// published, never RMW'd). sc0sc1 polls read the coherence point. Self-drains.
__device__ __forceinline__ void waitg(const int* slots, int tgt, int lane) {
  const int* p = slots + (lane & 31);
  int it = 0;
  for (;;) {
    int v;
    asm volatile("global_load_dword %0, %1, off sc0 sc1\n\ts_waitcnt vmcnt(0)"
                 : "=v"(v) : "v"(p) : "memory");
    if (__all(v >= tgt)) break;
    __builtin_amdgcn_s_sleep(1);
    if (++it > 4000000) break;      // deadlock bug -> fast fail, not hang
  }
}

#define LOADC(dst, ptr) \
  asm volatile("global_load_dwordx4 %0, %1, off sc0 sc1" : "=v"(dst) : "v"(ptr))
#define LOADN(dst, ptr) \
  asm volatile("global_load_dwordx4 %0, %1, off" : "=v"(dst) : "v"(ptr))
#define STORE_H2(ptr, v32) \
  asm volatile("global_store_short %0, %1, off sc0 sc1" :: "v"(ptr), "v"(v32))
#define STORE_D(ptr, v32) \
  asm volatile("global_store_dword %0, %1, off sc0 sc1" :: "v"(ptr), "v"(v32))
#define WAITV(n) do { asm volatile("s_waitcnt vmcnt(" #n ")" ::: "memory"); \
                      __builtin_amdgcn_sched_barrier(0); } while (0)
#define MM(a, b, c) c = __builtin_amdgcn_mfma_f32_16x16x32_bf16(a, b, c, 0, 0, 0)

// Persistent dataflow GRU — round-8 proven structure (LDS weights, row-major
// sc0sc1 h-ring, scattered STORE_H2 epilogue, RMW-free done[] flags) with
// SPLIT-WAIT / GH-FIRST scheduling:
//   wait W2(own t-1)+W3(WAR) -> gh pass (reads own h(t-1), no W1 dependency)
//   -> wave-0 polls W1(l-1 done t) -> gi pass (reads A).
// The inter-layer critical path drops from detect+512KB+384MFMA to
// detect+256KB+192MFMA per hop; gh reads overlap the producer's tail.
__global__ __launch_bounds__(256, 1) void gru_persist12(
    const float* __restrict__ x,     // [B,T,A,H] f32 (fallback)
    const short* __restrict__ xb,    // [B,T,A,H] bf16 or nullptr
    const short* __restrict__ wbih,  // [L,3H,H] bf16
    const short* __restrict__ wbhh,  // [L,3H,H] bf16
    const float* __restrict__ bih,   // [L,3H]
    const float* __restrict__ bhh,   // [L,3H]
    short* hb,                       // [2][L][512][512] bf16 parity ring
    const int* __restrict__ valid,   // [B,T,A] int32
    float* __restrict__ y,           // [B,T,A,H] f32
    int* done) {                     // [6][32] monotonic counters
  __shared__ char wlds[98304];

  const int bid = blockIdx.x;
  const int xcd = bid & 7;
  const int q = bid >> 3;            // 0..23
  const int l = q % 3;
  const int u = q / 3;               // 0..7
  const int rb = u & 1;
  const int cb = (u >> 1) * 8 + xcd; // 0..31
  const int c0 = cb * 16;
  const int R0 = rb * 256;
  const int gi = l * 2 + rb;

  const int tid = threadIdx.x;
  const int w = tid >> 6;
  const int lane = tid & 63;
  const int lrow = lane & 15;
  const int kgrp = lane >> 4;

  const short* wih_l = wbih + (size_t)l * H3c * Hc;
  const short* whh_l = wbhh + (size_t)l * H3c * Hc;

  // ---- one-time LDS weight fill: frag j = m*16+ks, lane-linear ----
#pragma unroll
  for (int j4 = 0; j4 < 24; ++j4) {
    int j = j4 * 4 + w;
    int m = j >> 4, ks = j & 15;
    int g = (m < 3) ? m : m - 3;
    int n = g * Hc + c0 + lrow;
    const short* src = ((m < 3) ? wih_l : whh_l) + (size_t)n * Hc + ks * 32 + kgrp * 8;
    *(bf16x8*)(wlds + (size_t)j * 1024 + lane * 16) = *(const bf16x8*)src;
  }
  __syncthreads();

  const char* wl = wlds + (lane << 4);

  const float* bihl = bih + l * H3c;
  const float* bhhl = bhh + l * H3c;
  const int c = c0 + lrow;
  const float bi0 = bihl[c], bi1 = bihl[Hc + c], bi2 = bihl[2 * Hc + c];
  const float bh0 = bhhl[c], bh1 = bhhl[Hc + c], bh2 = bhhl[2 * Hc + c];

  f32x4 hreg[4];
#pragma unroll
  for (int rf = 0; rf < 4; ++rf) hreg[rf] = f32x4{0.f, 0.f, 0.f, 0.f};

  WAITV(0);                          // setup loads drained before counted regions

  for (int t = 0; t < Tc; ++t) {
    // Phase-0 waits: W2 (own t-1: hprev RAW + own-slot WAR via siblings),
    //                W3 (layer l+1 read our t-2 slot: WAR). W1 deferred.
    if (w == 1 && t > 0)           waitg(done + gi * 32, t, lane);
    if (w == 2 && l < 2 && t >= 2) waitg(done + ((l + 1) * 2 + rb) * 32, t - 1, lane);
    __syncthreads();

    const int par = t & 1;
    const short* hprev = hb + (size_t)(1 - par) * HSLOT + (size_t)l * HLAY;

    const short* pH[4];
    const short* pA[4] = {nullptr, nullptr, nullptr, nullptr};
    const float* pXf[4] = {x, x, x, x};
#pragma unroll
    for (int rf = 0; rf < 4; ++rf) {
      int row = R0 + w * 64 + rf * 16 + lrow;
      pH[rf] = hprev + (size_t)row * Hc;
      if (l > 0) {
        pA[rf] = hb + (size_t)par * HSLOT + (size_t)(l - 1) * HLAY + (size_t)row * Hc;
      } else {
        int bb = row >> 6, aa = row & 63;
        size_t rofs = ((size_t)bb * Tc + t) * 64 + aa;
        if (xb) pA[rf] = xb + rofs * Hc;
        pXf[rf] = x + rofs * Hc;
      }
    }

    f32x4 acc[6][4];
#pragma unroll
    for (int m = 0; m < 6; ++m)
#pragma unroll
      for (int rf = 0; rf < 4; ++rf) acc[m][rf] = f32x4{0.f, 0.f, 0.f, 0.f};

    // per-pass macros: 8 loads per ISSUE group (4 rf x 2 k2), depth-16 dbuf
#define ISSUE_H(H_, g2)                                                            \
      { _Pragma("unroll") for (int rf = 0; rf < 4; ++rf)                           \
          _Pragma("unroll") for (int k2 = 0; k2 < 2; ++k2) {                       \
            const int ke = ((g2) * 2 + k2) * 32 + (kgrp << 3);                     \
            LOADC(H_[rf][k2], pH[rf] + ke);                                        \
          } }
#define ISSUE_AC(A_, g2)                                                           \
      { _Pragma("unroll") for (int rf = 0; rf < 4; ++rf)                           \
          _Pragma("unroll") for (int k2 = 0; k2 < 2; ++k2) {                       \
            const int ke = ((g2) * 2 + k2) * 32 + (kgrp << 3);                     \
            LOADC(A_[rf][k2], pA[rf] + ke);                                        \
          } }
#define ISSUE_AN(A_, g2)                                                           \
      { _Pragma("unroll") for (int rf = 0; rf < 4; ++rf)                           \
          _Pragma("unroll") for (int k2 = 0; k2 < 2; ++k2) {                       \
            const int ke = ((g2) * 2 + k2) * 32 + (kgrp << 3);                     \
            LOADN(A_[rf][k2], pA[rf] + ke);                                        \
          } }
#define CONSUME_H(H_, g2)                                                          \
      { _Pragma("unroll") for (int k2 = 0; k2 < 2; ++k2) {                         \
          const int ks = (g2) * 2 + k2;                                            \
          bf16x8 Bg3 = *(const bf16x8*)(wl + ((3 * 16 + ks) << 10));               \
          bf16x8 Bg4 = *(const bf16x8*)(wl + ((4 * 16 + ks) << 10));               \
          bf16x8 Bg5 = *(const bf16x8*)(wl + ((5 * 16 + ks) << 10));               \
          _Pragma("unroll") for (int rf = 0; rf < 4; ++rf) {                       \
            MM(H_[rf][k2], Bg3, acc[3][rf]);                                       \
            MM(H_[rf][k2], Bg4, acc[4][rf]);                                       \
            MM(H_[rf][k2], Bg5, acc[5][rf]);                                       \
          } } }
#define CONSUME_A(A_, g2)                                                          \
      { _Pragma("unroll") for (int k2 = 0; k2 < 2; ++k2) {                         \
          const int ks = (g2) * 2 + k2;                                            \
          bf16x8 Bg0 = *(const bf16x8*)(wl + ((0 * 16 + ks) << 10));               \
          bf16x8 Bg1 = *(const bf16x8*)(wl + ((1 * 16 + ks) << 10));               \
          bf16x8 Bg2 = *(const bf16x8*)(wl + ((2 * 16 + ks) << 10));               \
          _Pragma("unroll") for (int rf = 0; rf < 4; ++rf) {                       \
            MM(A_[rf][k2], Bg0, acc[0][rf]);                                       \
            MM(A_[rf][k2], Bg1, acc[1][rf]);                                       \
            MM(A_[rf][k2], Bg2, acc[2][rf]);                                       \
          } } }
#define PASS(ISS, CONS)                                                            \
      { bf16x8 Ra[4][2], Rb[4][2];                                                 \
        ISS(Ra, 0);                                                                \
        _Pragma("unroll") for (int g2 = 0; g2 < 8; g2 += 2) {                      \
          ISS(Rb, g2 + 1);                                                         \
          WAITV(8);                                                                \
          CONS(Ra, g2);                                                            \
          if (g2 + 2 < 8) {                                                        \
            ISS(Ra, g2 + 2);                                                       \
            WAITV(8);                                                              \
          } else {                                                                 \
            WAITV(0);                                                              \
          }                                                                        \
          CONS(Rb, g2 + 1);                                                        \
        } }

    __builtin_amdgcn_sched_barrier(0);
    if (l > 0) {
      PASS(ISSUE_H, CONSUME_H)                 // gh while producer finishes
      if (w == 0) waitg(done + ((l - 1) * 2 + rb) * 32, t + 1, lane);  // W1
      __syncthreads();
      __builtin_amdgcn_sched_barrier(0);
      PASS(ISSUE_AC, CONSUME_A)                // gi once A is published
    } else if (xb) {
      PASS(ISSUE_H, CONSUME_H)
      PASS(ISSUE_AN, CONSUME_A)                // x static: no W1
    } else {                                   // fallback: single-buffered drains
      bf16x8 Ha[4][2];
#pragma unroll
      for (int g2 = 0; g2 < 8; ++g2) {
        ISSUE_H(Ha, g2);
        WAITV(0);
        CONSUME_H(Ha, g2);
      }
#pragma unroll
      for (int g2 = 0; g2 < 8; ++g2) {
        bf16x8 Aa[4][2];
#pragma unroll
        for (int rf = 0; rf < 4; ++rf)
#pragma unroll
          for (int k2 = 0; k2 < 2; ++k2) {
            const int ks = g2 * 2 + k2;
            const float* _px = pXf[rf] + ks * 32 + (kgrp << 3);
            f32x4 v0 = *(const f32x4*)_px;
            f32x4 v1 = *(const f32x4*)(_px + 4);
            bf16x8 t_;
#pragma unroll
            for (int e = 0; e < 4; ++e) {
              t_[e] = (short)f2bf(v0[e]); t_[4 + e] = (short)f2bf(v1[e]);
            }
            Aa[rf][k2] = t_;
          }
        CONSUME_A(Aa, g2);
      }
    }
    __builtin_amdgcn_sched_barrier(0);

    // epilogue (r8 proven form): C/D map col=lane&15, row=(lane>>4)*4+reg
    short* hout = hb + (size_t)par * HSLOT + (size_t)l * HLAY;
#pragma unroll
    for (int rf = 0; rf < 4; ++rf) {
#pragma unroll
      for (int rr = 0; rr < 4; ++rr) {
        int rowg = R0 + w * 64 + rf * 16 + kgrp * 4 + rr;
        int bb = rowg >> 6, aa = rowg & 63;
        size_t vofs = ((size_t)bb * Tc + t) * 64 + aa;
        int vld = valid[vofs];
        float ir = acc[0][rf][rr] + bi0;
        float iz = acc[1][rf][rr] + bi1;
        float in_ = acc[2][rf][rr] + bi2;
        float hr = acc[3][rf][rr] + bh0;
        float hz = acc[4][rf][rr] + bh1;
        float hn = acc[5][rf][rr] + bh2;
        float rg = 1.0f / (1.0f + __expf(-(ir + hr)));
        float zg = 1.0f / (1.0f + __expf(-(iz + hz)));
        float ng = tanhf(in_ + rg * hn);
        float hnew = (1.0f - zg) * ng + zg * hreg[rf][rr];
        if (!vld) hnew = 0.0f;
        hreg[rf][rr] = hnew;
        int hv = (int)f2bf(hnew);
        STORE_H2(hout + (size_t)rowg * Hc + c, hv);
        if (l == 2) y[vofs * Hc + c] = hnew;
      }
    }

    asm volatile("s_waitcnt vmcnt(0)" ::: "memory");   // sc stores + y drained
    __syncthreads();                                   // all waves' stores done
    if (tid == 0) {                  // publish: single sc STORE, no RMW
      int v = t + 1;
      STORE_D(done + gi * 32 + cb, v);
    }
    WAITV(0);   // drain publish store: vmcnt clean for next counted region
  }
}

extern "C" void kernel_launch(void* const* d_in, const int* in_sizes, int n_in,
                              void* d_out, int out_size, void* d_ws, size_t ws_size,
                              hipStream_t stream) {
  const float* x = (const float*)d_in[0];
  const int* valid = (const int*)d_in[1];
  const float* w_ih = (const float*)d_in[2];
  const float* w_hh = (const float*)d_in[3];
  const float* b_ih = (const float*)d_in[4];
  const float* b_hh = (const float*)d_in[5];
  float* y = (float*)d_out;

  char* ws = (char*)d_ws;
  const size_t welems = (size_t)Lc * H3c * Hc;            // 2,359,296
  unsigned short* wbih = (unsigned short*)ws;
  unsigned short* wbhh = (unsigned short*)(ws + welems * 2);
  short* hb = (short*)(ws + welems * 4);                  // 3.0 MB ring
  const size_t hb_bytes = (size_t)2 * HSLOT * 2;
  int* done = (int*)(ws + welems * 4 + hb_bytes);         // [6][32] = 768 B
  const size_t flags_bytes = 4800;
  const size_t xb_off = welems * 4 + hb_bytes + flags_bytes;  // 16B aligned
  const size_t xelems = (size_t)8 * Tc * 64 * Hc;         // 26,214,400
  const bool big = ws_size >= xb_off + xelems * 2;
  unsigned short* xbf = big ? (unsigned short*)(ws + xb_off) : nullptr;

  int n4w = (int)(welems / 4);
  conv_bf16<<<(n4w + 255) / 256, 256, 0, stream>>>(w_ih, wbih, n4w);
  conv_bf16<<<(n4w + 255) / 256, 256, 0, stream>>>(w_hh, wbhh, n4w);
  if (big) {
    int n4x = (int)(xelems / 4);
    conv_bf16<<<(n4x + 255) / 256, 256, 0, stream>>>(x, xbf, n4x);
  }
  (void)hipMemsetAsync(hb, 0, hb_bytes + flags_bytes, stream);

  gru_persist12<<<192, 256, 0, stream>>>(x, (const short*)xbf,
                                         (const short*)wbih, (const short*)wbhh,
                                         b_ih, b_hh, hb, valid, y, done);
}

// Round 14
// 2537.803 us; speedup vs baseline: 2.2658x; 1.0509x over previous
//
#include <hip/hip_runtime.h>

#define Tc 100
#define Hc 512
#define Lc 3
#define H3c 1536
#define HLAY (Hc*Hc)            // elems per layer slice of an hbX parity slot
#define HSLOT (Lc*HLAY)         // elems per hbX parity slot
#define HLPAR (6*256*512)       // elems per hbl parity slot (6 groups x 256 x 512)

typedef short bf16x8 __attribute__((ext_vector_type(8)));
typedef float f32x4 __attribute__((ext_vector_type(4)));

__device__ __forceinline__ unsigned short f2bf(float f) {
  unsigned int u = __float_as_uint(f);
  u += 0x7FFFu + ((u >> 16) & 1u);   // round-to-nearest-even
  return (unsigned short)(u >> 16);
}

__global__ __launch_bounds__(256) void conv_bf16(const float* __restrict__ src,
                                                 unsigned short* __restrict__ dst,
                                                 int n4) {
  int i = blockIdx.x * 256 + threadIdx.x;
  if (i >= n4) return;
  f32x4 v = *(const f32x4*)(src + (size_t)i * 4);
  ushort4 o;
  o.x = f2bf(v[0]); o.y = f2bf(v[1]); o.z = f2bf(v[2]); o.w = f2bf(v[3]);
  *(ushort4*)(dst + (size_t)i * 4) = o;
}

// Lane-parallel group wait on 32 monotonic per-producer counters (store-
// published, never RMW'd). sc0sc1 polls read the coherence point. Self-drains.
__device__ __forceinline__ void waitg(const int* slots, int tgt, int lane) {
  const int* p = slots + (lane & 31);
  int it = 0;
  for (;;) {
    int v;
    asm volatile("global_load_dword %0, %1, off sc0 sc1\n\ts_waitcnt vmcnt(0)"
                 : "=v"(v) : "v"(p) : "memory");
    if (__all(v >= tgt)) break;
    __builtin_amdgcn_s_sleep(1);
    if (++it > 4000000) break;      // deadlock bug -> fast fail, not hang
  }
}

#define LOADC(dst, ptr) \
  asm volatile("global_load_dwordx4 %0, %1, off sc0 sc1" : "=v"(dst) : "v"(ptr))
#define LOADL(dst, ptr) \
  asm volatile("global_load_dwordx4 %0, %1, off sc0" : "=v"(dst) : "v"(ptr))
#define LOADN(dst, ptr) \
  asm volatile("global_load_dwordx4 %0, %1, off" : "=v"(dst) : "v"(ptr))
#define STORE_H2(ptr, v32) \
  asm volatile("global_store_short %0, %1, off sc0 sc1" :: "v"(ptr), "v"(v32))
#define STORE_HL(ptr, v32) \
  asm volatile("global_store_short %0, %1, off sc0" :: "v"(ptr), "v"(v32))
#define STORE_D(ptr, v32) \
  asm volatile("global_store_dword %0, %1, off sc0 sc1" :: "v"(ptr), "v"(v32))
#define WAITV(n) do { asm volatile("s_waitcnt vmcnt(" #n ")" ::: "memory"); \
                      __builtin_amdgcn_sched_barrier(0); } while (0)
#define MM(a, b, c) c = __builtin_amdgcn_mfma_f32_16x16x32_bf16(a, b, c, 0, 0, 0)

// Persistent dataflow GRU — r13 structure with XCD-LOCAL H RECURRENCE:
//   bid = cb*8 + gi  (gi = l*2+rb; bid&7>=6 exits) -> group gi's 32 blocks
//   fill XCD gi. h is dual-stored: sc0 -> hbl (XCD-local L2 ring, feeds own
//   group's gh pass next step, never touches L3) and sc0sc1 -> hbX (L3 ring,
//   feeds layer l+1's gi pass). H-pass reads hbl with sc0 (L2-scope).
//   t=0 skips the H-pass (h=0 -> gh=bias), so hbl needs no init.
//   Cuts L3-fabric read volume ~in half (98 -> ~50 MB/stage) — the measured
//   3.8 TB/s fabric saturation is the roofline of r8/r13.
__global__ __launch_bounds__(256, 1) void gru_persist13(
    const float* __restrict__ x,     // [B,T,A,H] f32 (fallback)
    const short* __restrict__ xb,    // [B,T,A,H] bf16 or nullptr
    const short* __restrict__ wbih,  // [L,3H,H] bf16
    const short* __restrict__ wbhh,  // [L,3H,H] bf16
    const float* __restrict__ bih,   // [L,3H]
    const float* __restrict__ bhh,   // [L,3H]
    short* hb,                       // [2][L][512][512] bf16 L3 ring (sc0sc1)
    short* hbl,                      // [2][6][256][512] bf16 XCD-local ring (sc0)
    const int* __restrict__ valid,   // [B,T,A] int32
    float* __restrict__ y,           // [B,T,A,H] f32
    int* done) {                     // [6][32] monotonic counters
  __shared__ char wlds[98304];

  const int bid = blockIdx.x;
  const int gi = bid & 7;            // group -> XCD gi
  if (gi >= 6) return;               // 64 dummy blocks (XCDs 6,7 idle)
  const int cb = bid >> 3;           // 0..31
  const int l = gi >> 1;
  const int rb = gi & 1;
  const int c0 = cb * 16;
  const int R0 = rb * 256;

  const int tid = threadIdx.x;
  const int w = tid >> 6;
  const int lane = tid & 63;
  const int lrow = lane & 15;
  const int kgrp = lane >> 4;

  const short* wih_l = wbih + (size_t)l * H3c * Hc;
  const short* whh_l = wbhh + (size_t)l * H3c * Hc;

  // ---- one-time LDS weight fill: frag j = m*16+ks, lane-linear ----
#pragma unroll
  for (int j4 = 0; j4 < 24; ++j4) {
    int j = j4 * 4 + w;
    int m = j >> 4, ks = j & 15;
    int g = (m < 3) ? m : m - 3;
    int n = g * Hc + c0 + lrow;
    const short* src = ((m < 3) ? wih_l : whh_l) + (size_t)n * Hc + ks * 32 + kgrp * 8;
    *(bf16x8*)(wlds + (size_t)j * 1024 + lane * 16) = *(const bf16x8*)src;
  }
  __syncthreads();

  const char* wl = wlds + (lane << 4);

  const float* bihl = bih + l * H3c;
  const float* bhhl = bhh + l * H3c;
  const int c = c0 + lrow;
  const float bi0 = bihl[c], bi1 = bihl[Hc + c], bi2 = bihl[2 * Hc + c];
  const float bh0 = bhhl[c], bh1 = bhhl[Hc + c], bh2 = bhhl[2 * Hc + c];

  f32x4 hreg[4];
#pragma unroll
  for (int rf = 0; rf < 4; ++rf) hreg[rf] = f32x4{0.f, 0.f, 0.f, 0.f};

  WAITV(0);                          // setup loads drained before counted regions

  for (int t = 0; t < Tc; ++t) {
    // Phase-0 waits: W2 (own t-1), W3 (layer l+1 WAR on hbX). W1 deferred.
    if (w == 1 && t > 0)           waitg(done + gi * 32, t, lane);
    if (w == 2 && l < 2 && t >= 2) waitg(done + ((l + 1) * 2 + rb) * 32, t - 1, lane);
    __syncthreads();

    const int par = t & 1;

    const short* pHL[4];             // hbl: XCD-local, group-local rows 0..255
    const short* pA[4] = {nullptr, nullptr, nullptr, nullptr};
    const float* pXf[4] = {x, x, x, x};
    {
      const short* hprevL = hbl + (size_t)(1 - par) * HLPAR + (size_t)gi * 131072;
#pragma unroll
      for (int rf = 0; rf < 4; ++rf) {
        int rowl = w * 64 + rf * 16 + lrow;        // local row
        pHL[rf] = hprevL + (size_t)rowl * Hc;
        int row = R0 + rowl;                       // global row
        if (l > 0) {
          pA[rf] = hb + (size_t)par * HSLOT + (size_t)(l - 1) * HLAY + (size_t)row * Hc;
        } else {
          int bb = row >> 6, aa = row & 63;
          size_t rofs = ((size_t)bb * Tc + t) * 64 + aa;
          if (xb) pA[rf] = xb + rofs * Hc;
          pXf[rf] = x + rofs * Hc;
        }
      }
    }

    f32x4 acc[6][4];
#pragma unroll
    for (int m = 0; m < 6; ++m)
#pragma unroll
      for (int rf = 0; rf < 4; ++rf) acc[m][rf] = f32x4{0.f, 0.f, 0.f, 0.f};

#define ISSUE_HL(H_, g2)                                                           \
      { _Pragma("unroll") for (int rf = 0; rf < 4; ++rf)                           \
          _Pragma("unroll") for (int k2 = 0; k2 < 2; ++k2) {                       \
            const int ke = ((g2) * 2 + k2) * 32 + (kgrp << 3);                     \
            LOADL(H_[rf][k2], pHL[rf] + ke);                                       \
          } }
#define ISSUE_AC(A_, g2)                                                           \
      { _Pragma("unroll") for (int rf = 0; rf < 4; ++rf)                           \
          _Pragma("unroll") for (int k2 = 0; k2 < 2; ++k2) {                       \
            const int ke = ((g2) * 2 + k2) * 32 + (kgrp << 3);                     \
            LOADC(A_[rf][k2], pA[rf] + ke);                                        \
          } }
#define ISSUE_AN(A_, g2)                                                           \
      { _Pragma("unroll") for (int rf = 0; rf < 4; ++rf)                           \
          _Pragma("unroll") for (int k2 = 0; k2 < 2; ++k2) {                       \
            const int ke = ((g2) * 2 + k2) * 32 + (kgrp << 3);                     \
            LOADN(A_[rf][k2], pA[rf] + ke);                                        \
          } }
#define CONSUME_H(H_, g2)                                                          \
      { _Pragma("unroll") for (int k2 = 0; k2 < 2; ++k2) {                         \
          const int ks = (g2) * 2 + k2;                                            \
          bf16x8 Bg3 = *(const bf16x8*)(wl + ((3 * 16 + ks) << 10));               \
          bf16x8 Bg4 = *(const bf16x8*)(wl + ((4 * 16 + ks) << 10));               \
          bf16x8 Bg5 = *(const bf16x8*)(wl + ((5 * 16 + ks) << 10));               \
          _Pragma("unroll") for (int rf = 0; rf < 4; ++rf) {                       \
            MM(H_[rf][k2], Bg3, acc[3][rf]);                                       \
            MM(H_[rf][k2], Bg4, acc[4][rf]);                                       \
            MM(H_[rf][k2], Bg5, acc[5][rf]);                                       \
          } } }
#define CONSUME_A(A_, g2)                                                          \
      { _Pragma("unroll") for (int k2 = 0; k2 < 2; ++k2) {                         \
          const int ks = (g2) * 2 + k2;                                            \
          bf16x8 Bg0 = *(const bf16x8*)(wl + ((0 * 16 + ks) << 10));               \
          bf16x8 Bg1 = *(const bf16x8*)(wl + ((1 * 16 + ks) << 10));               \
          bf16x8 Bg2 = *(const bf16x8*)(wl + ((2 * 16 + ks) << 10));               \
          _Pragma("unroll") for (int rf = 0; rf < 4; ++rf) {                       \
            MM(A_[rf][k2], Bg0, acc[0][rf]);                                       \
            MM(A_[rf][k2], Bg1, acc[1][rf]);                                       \
            MM(A_[rf][k2], Bg2, acc[2][rf]);                                       \
          } } }
#define PASS(ISS, CONS)                                                            \
      { bf16x8 Ra[4][2], Rb[4][2];                                                 \
        ISS(Ra, 0);                                                                \
        _Pragma("unroll") for (int g2 = 0; g2 < 8; g2 += 2) {                      \
          ISS(Rb, g2 + 1);                                                         \
          WAITV(8);                                                                \
          CONS(Ra, g2);                                                            \
          if (g2 + 2 < 8) {                                                        \
            ISS(Ra, g2 + 2);                                                       \
            WAITV(8);                                                              \
          } else {                                                                 \
            WAITV(0);                                                              \
          }                                                                        \
          CONS(Rb, g2 + 1);                                                        \
        } }

    __builtin_amdgcn_sched_barrier(0);
    if (t > 0) {                     // gh pass: XCD-local L2 reads (sc0).
      PASS(ISSUE_HL, CONSUME_H)      // t=0: h=0 -> gh=bias, pass skipped.
    }
    if (l > 0) {
      if (w == 0) waitg(done + ((l - 1) * 2 + rb) * 32, t + 1, lane);  // W1
      __syncthreads();
      __builtin_amdgcn_sched_barrier(0);
      PASS(ISSUE_AC, CONSUME_A)      // gi once A is published (L3 sc reads)
    } else if (xb) {
      PASS(ISSUE_AN, CONSUME_A)      // x static: no W1, normal cached
    } else {                         // fallback: f32 x, compiler loads
#pragma unroll
      for (int g2 = 0; g2 < 8; ++g2) {
        bf16x8 Aa[4][2];
#pragma unroll
        for (int rf = 0; rf < 4; ++rf)
#pragma unroll
          for (int k2 = 0; k2 < 2; ++k2) {
            const int ks = g2 * 2 + k2;
            const float* _px = pXf[rf] + ks * 32 + (kgrp << 3);
            f32x4 v0 = *(const f32x4*)_px;
            f32x4 v1 = *(const f32x4*)(_px + 4);
            bf16x8 t_;
#pragma unroll
            for (int e = 0; e < 4; ++e) {
              t_[e] = (short)f2bf(v0[e]); t_[4 + e] = (short)f2bf(v1[e]);
            }
            Aa[rf][k2] = t_;
          }
        WAITV(0);
        CONSUME_A(Aa, g2);
      }
    }
    __builtin_amdgcn_sched_barrier(0);

    // epilogue: C/D map col=lane&15, row=(lane>>4)*4+reg (m89-verified).
    // Dual store: sc0 -> hbl (own XCD L2), sc0sc1 -> hbX (L3, for layer l+1).
    short* hout = hb + (size_t)par * HSLOT + (size_t)l * HLAY;
    short* houtL = hbl + (size_t)par * HLPAR + (size_t)gi * 131072;
#pragma unroll
    for (int rf = 0; rf < 4; ++rf) {
#pragma unroll
      for (int rr = 0; rr < 4; ++rr) {
        int mloc = w * 64 + rf * 16 + kgrp * 4 + rr;   // local row 0..255
        int rowg = R0 + mloc;
        int bb = rowg >> 6, aa = rowg & 63;
        size_t vofs = ((size_t)bb * Tc + t) * 64 + aa;
        int vld = valid[vofs];
        float ir = acc[0][rf][rr] + bi0;
        float iz = acc[1][rf][rr] + bi1;
        float in_ = acc[2][rf][rr] + bi2;
        float hr = acc[3][rf][rr] + bh0;
        float hz = acc[4][rf][rr] + bh1;
        float hn = acc[5][rf][rr] + bh2;
        float rg = 1.0f / (1.0f + __expf(-(ir + hr)));
        float zg = 1.0f / (1.0f + __expf(-(iz + hz)));
        float ng = tanhf(in_ + rg * hn);
        float hnew = (1.0f - zg) * ng + zg * hreg[rf][rr];
        if (!vld) hnew = 0.0f;
        hreg[rf][rr] = hnew;
        int hv = (int)f2bf(hnew);
        STORE_HL(houtL + (size_t)mloc * Hc + c, hv);
        if (l < 2) STORE_H2(hout + (size_t)rowg * Hc + c, hv);
        else       y[vofs * Hc + c] = hnew;   // l=2: only y consumer
      }
    }

    asm volatile("s_waitcnt vmcnt(0)" ::: "memory");   // all stores retired
    __syncthreads();                                   // all waves' stores done
    if (tid == 0) {                  // publish: single sc STORE, no RMW
      int v = t + 1;
      STORE_D(done + gi * 32 + cb, v);
    }
    WAITV(0);   // drain publish store: vmcnt clean for next counted region
  }
}

extern "C" void kernel_launch(void* const* d_in, const int* in_sizes, int n_in,
                              void* d_out, int out_size, void* d_ws, size_t ws_size,
                              hipStream_t stream) {
  const float* x = (const float*)d_in[0];
  const int* valid = (const int*)d_in[1];
  const float* w_ih = (const float*)d_in[2];
  const float* w_hh = (const float*)d_in[3];
  const float* b_ih = (const float*)d_in[4];
  const float* b_hh = (const float*)d_in[5];
  float* y = (float*)d_out;

  char* ws = (char*)d_ws;
  const size_t welems = (size_t)Lc * H3c * Hc;            // 2,359,296
  unsigned short* wbih = (unsigned short*)ws;
  unsigned short* wbhh = (unsigned short*)(ws + welems * 2);
  short* hb = (short*)(ws + welems * 4);                  // 3.0 MB L3 ring
  const size_t hb_bytes = (size_t)2 * HSLOT * 2;
  int* done = (int*)(ws + welems * 4 + hb_bytes);         // [6][32] = 768 B
  const size_t flags_bytes = 4800;
  const size_t hbl_off = welems * 4 + hb_bytes + flags_bytes;
  const size_t hbl_bytes = (size_t)2 * HLPAR * 2;         // 3.0 MB local ring
  short* hbl = (short*)(ws + hbl_off);
  const size_t xb_off = hbl_off + hbl_bytes;              // 16B aligned
  const size_t xelems = (size_t)8 * Tc * 64 * Hc;         // 26,214,400
  const bool big = ws_size >= xb_off + xelems * 2;
  unsigned short* xbf = big ? (unsigned short*)(ws + xb_off) : nullptr;

  int n4w = (int)(welems / 4);
  conv_bf16<<<(n4w + 255) / 256, 256, 0, stream>>>(w_ih, wbih, n4w);
  conv_bf16<<<(n4w + 255) / 256, 256, 0, stream>>>(w_hh, wbhh, n4w);
  if (big) {
    int n4x = (int)(xelems / 4);
    conv_bf16<<<(n4x + 255) / 256, 256, 0, stream>>>(x, xbf, n4x);
  }
  (void)hipMemsetAsync(hb, 0, hb_bytes + flags_bytes, stream);  // hbl needs no init

  gru_persist13<<<256, 256, 0, stream>>>(x, (const short*)xbf,
                                         (const short*)wbih, (const short*)wbhh,
                                         b_ih, b_hh, hb, hbl, valid, y, done);
}

// Round 15
// 2049.275 us; speedup vs baseline: 2.8060x; 1.2384x over previous
//
#include <hip/hip_runtime.h>

#define Tc 100
#define Hc 512
#define Lc 3
#define H3c 1536
#define HLAY (Hc*Hc)            // elems per layer slice of an hbX parity slot
#define HSLOT (Lc*HLAY)         // elems per hbX parity slot
#define HLPAR (6*256*512)       // elems per hbl parity slot (6 groups x 256 x 512)

typedef short bf16x8 __attribute__((ext_vector_type(8)));
typedef float f32x4 __attribute__((ext_vector_type(4)));

__device__ __forceinline__ unsigned short f2bf(float f) {
  unsigned int u = __float_as_uint(f);
  u += 0x7FFFu + ((u >> 16) & 1u);   // round-to-nearest-even
  return (unsigned short)(u >> 16);
}

__global__ __launch_bounds__(256) void conv_bf16(const float* __restrict__ src,
                                                 unsigned short* __restrict__ dst,
                                                 int n4) {
  int i = blockIdx.x * 256 + threadIdx.x;
  if (i >= n4) return;
  f32x4 v = *(const f32x4*)(src + (size_t)i * 4);
  ushort4 o;
  o.x = f2bf(v[0]); o.y = f2bf(v[1]); o.z = f2bf(v[2]); o.w = f2bf(v[3]);
  *(ushort4*)(dst + (size_t)i * 4) = o;
}

// Lane-parallel group wait on 32 monotonic per-producer counters (store-
// published, never RMW'd). sc0sc1 polls read the coherence point. Self-drains.
// s_sleep(8) backoff halves flag-line poll pressure vs sleep(1).
__device__ __forceinline__ void waitg(const int* slots, int tgt, int lane) {
  const int* p = slots + (lane & 31);
  int it = 0;
  for (;;) {
    int v;
    asm volatile("global_load_dword %0, %1, off sc0 sc1\n\ts_waitcnt vmcnt(0)"
                 : "=v"(v) : "v"(p) : "memory");
    if (__all(v >= tgt)) break;
    __builtin_amdgcn_s_sleep(8);
    if (++it > 1000000) break;      // deadlock bug -> fast fail, not hang
  }
}

#define LOADC(dst, ptr) \
  asm volatile("global_load_dwordx4 %0, %1, off sc0 sc1" : "=v"(dst) : "v"(ptr))
#define LOADL(dst, ptr) \
  asm volatile("global_load_dwordx4 %0, %1, off sc0" : "=v"(dst) : "v"(ptr))
#define LOADN(dst, ptr) \
  asm volatile("global_load_dwordx4 %0, %1, off" : "=v"(dst) : "v"(ptr))
#define STORE_H2(ptr, v32) \
  asm volatile("global_store_short %0, %1, off sc0 sc1" :: "v"(ptr), "v"(v32))
#define STORE_HL(ptr, v32) \
  asm volatile("global_store_short %0, %1, off sc0" :: "v"(ptr), "v"(v32))
#define STORE_D(ptr, v32) \
  asm volatile("global_store_dword %0, %1, off sc0 sc1" :: "v"(ptr), "v"(v32))
#define WAITV(n) do { asm volatile("s_waitcnt vmcnt(" #n ")" ::: "memory"); \
                      __builtin_amdgcn_sched_barrier(0); } while (0)
#define MM(a, b, c) c = __builtin_amdgcn_mfma_f32_16x16x32_bf16(a, b, c, 0, 0, 0)

// Persistent dataflow GRU — r14 data path (XCD-local hbl ring + L3 hb ring,
// LDS weights, RMW-free done[] flags) at 4x OCCUPANCY: 1024-thread blocks
// (16 waves, 4 waves/SIMD) instead of 256 (1 wave/SIMD). r14's counters
// (MfmaUtil 7.5%, VALU 9.3%, idle 83%, period insensitive to traffic) showed
// the stage cost is EXPOSED LATENCY at 1 wave/SIMD, not bandwidth. Same
// 256 rows x 16 cols per block; each wave now owns 16 rows (rf=1).
__global__ __launch_bounds__(1024, 4) void gru_persist14(
    const float* __restrict__ x,     // [B,T,A,H] f32 (fallback)
    const short* __restrict__ xb,    // [B,T,A,H] bf16 or nullptr
    const short* __restrict__ wbih,  // [L,3H,H] bf16
    const short* __restrict__ wbhh,  // [L,3H,H] bf16
    const float* __restrict__ bih,   // [L,3H]
    const float* __restrict__ bhh,   // [L,3H]
    short* hb,                       // [2][L][512][512] bf16 L3 ring (sc0sc1)
    short* hbl,                      // [2][6][256][512] bf16 XCD-local ring (sc0)
    const int* __restrict__ valid,   // [B,T,A] int32
    float* __restrict__ y,           // [B,T,A,H] f32
    int* done) {                     // [6][32] monotonic counters
  __shared__ char wlds[98304];

  const int bid = blockIdx.x;
  const int gi = bid & 7;            // group -> XCD gi
  if (gi >= 6) return;               // 64 dummy blocks (XCDs 6,7 idle)
  const int cb = bid >> 3;           // 0..31
  const int l = gi >> 1;
  const int rb = gi & 1;
  const int c0 = cb * 16;
  const int R0 = rb * 256;

  const int tid = threadIdx.x;
  const int w = tid >> 6;            // wave 0..15
  const int lane = tid & 63;
  const int lrow = lane & 15;
  const int kgrp = lane >> 4;

  const short* wih_l = wbih + (size_t)l * H3c * Hc;
  const short* whh_l = wbhh + (size_t)l * H3c * Hc;

  // ---- one-time LDS weight fill: frag j = m*16+ks, lane-linear ----
#pragma unroll
  for (int it = 0; it < 6; ++it) {
    int j = it * 16 + w;             // 96 fragments, one per wave-iteration
    int m = j >> 4, ks = j & 15;
    int g = (m < 3) ? m : m - 3;
    int n = g * Hc + c0 + lrow;
    const short* src = ((m < 3) ? wih_l : whh_l) + (size_t)n * Hc + ks * 32 + kgrp * 8;
    *(bf16x8*)(wlds + (size_t)j * 1024 + lane * 16) = *(const bf16x8*)src;
  }
  __syncthreads();

  const char* wl = wlds + (lane << 4);

  const float* bihl = bih + l * H3c;
  const float* bhhl = bhh + l * H3c;
  const int c = c0 + lrow;
  const float bi0 = bihl[c], bi1 = bihl[Hc + c], bi2 = bihl[2 * Hc + c];
  const float bh0 = bhhl[c], bh1 = bhhl[Hc + c], bh2 = bhhl[2 * Hc + c];

  f32x4 hreg = f32x4{0.f, 0.f, 0.f, 0.f};   // 4 outputs/thread

  WAITV(0);                          // setup loads drained before counted regions

  for (int t = 0; t < Tc; ++t) {
    // Phase-0 waits: W2 (own t-1), W3 (layer l+1 WAR on hbX). W1 deferred.
    if (w == 1 && t > 0)           waitg(done + gi * 32, t, lane);
    if (w == 2 && l < 2 && t >= 2) waitg(done + ((l + 1) * 2 + rb) * 32, t - 1, lane);
    __syncthreads();

    const int par = t & 1;
    const int rowl = w * 16 + lrow;  // group-local row 0..255

    const short* pHL = hbl + (size_t)(1 - par) * HLPAR + (size_t)gi * 131072
                       + (size_t)rowl * Hc;
    const short* pA = nullptr;
    const float* pXf = x;
    {
      int row = R0 + rowl;           // global row
      if (l > 0) {
        pA = hb + (size_t)par * HSLOT + (size_t)(l - 1) * HLAY + (size_t)row * Hc;
      } else {
        int bb = row >> 6, aa = row & 63;
        size_t rofs = ((size_t)bb * Tc + t) * 64 + aa;
        if (xb) pA = xb + rofs * Hc;
        pXf = x + rofs * Hc;
      }
    }

    f32x4 acc[6];
#pragma unroll
    for (int m = 0; m < 6; ++m) acc[m] = f32x4{0.f, 0.f, 0.f, 0.f};

    // rolling window-8 pass: issue 8, consume 4 per WAITV(4) step (literals)
#define ISS4(LOADM, P_, R_, b)                                                     \
      { _Pragma("unroll") for (int q = 0; q < 4; ++q) {                            \
          const int ks = (b) + q;                                                  \
          LOADM(R_[ks & 7], P_ + ks * 32 + (kgrp << 3));                           \
        } }
#define CON4(R_, b, M0)                                                            \
      { _Pragma("unroll") for (int q = 0; q < 4; ++q) {                            \
          const int ks = (b) + q;                                                  \
          bf16x8 B0 = *(const bf16x8*)(wl + (((M0) * 16 + ks) << 10));             \
          bf16x8 B1 = *(const bf16x8*)(wl + ((((M0) + 1) * 16 + ks) << 10));       \
          bf16x8 B2 = *(const bf16x8*)(wl + ((((M0) + 2) * 16 + ks) << 10));       \
          MM(R_[ks & 7], B0, acc[(M0)]);                                           \
          MM(R_[ks & 7], B1, acc[(M0) + 1]);                                       \
          MM(R_[ks & 7], B2, acc[(M0) + 2]);                                       \
        } }
#define PASS(LOADM, P_, M0)                                                        \
      { bf16x8 R_[8];                                                              \
        ISS4(LOADM, P_, R_, 0);  ISS4(LOADM, P_, R_, 4);                           \
        WAITV(4); CON4(R_, 0, M0);                                                 \
        ISS4(LOADM, P_, R_, 8);                                                    \
        WAITV(4); CON4(R_, 4, M0);                                                 \
        ISS4(LOADM, P_, R_, 12);                                                   \
        WAITV(4); CON4(R_, 8, M0);                                                 \
        WAITV(0); CON4(R_, 12, M0);                                                \
      }

    __builtin_amdgcn_sched_barrier(0);
    if (t > 0) {                     // gh pass: XCD-local L2 reads (sc0).
      PASS(LOADL, pHL, 3)            // t=0: h=0 -> gh=bias, pass skipped.
    }
    if (l > 0) {
      if (w == 0) waitg(done + ((l - 1) * 2 + rb) * 32, t + 1, lane);  // W1
      __syncthreads();
      __builtin_amdgcn_sched_barrier(0);
      PASS(LOADC, pA, 0)             // gi once A is published (L3 sc reads)
    } else if (xb) {
      PASS(LOADN, pA, 0)             // x static: no W1, normal cached
    } else {                         // fallback: f32 x via compiler loads
#pragma unroll
      for (int ks = 0; ks < 16; ++ks) {
        const float* _px = pXf + ks * 32 + (kgrp << 3);
        f32x4 v0 = *(const f32x4*)_px;
        f32x4 v1 = *(const f32x4*)(_px + 4);
        bf16x8 t_;
#pragma unroll
        for (int e = 0; e < 4; ++e) {
          t_[e] = (short)f2bf(v0[e]); t_[4 + e] = (short)f2bf(v1[e]);
        }
        bf16x8 B0 = *(const bf16x8*)(wl + ((0 * 16 + ks) << 10));
        bf16x8 B1 = *(const bf16x8*)(wl + ((1 * 16 + ks) << 10));
        bf16x8 B2 = *(const bf16x8*)(wl + ((2 * 16 + ks) << 10));
        MM(t_, B0, acc[0]);
        MM(t_, B1, acc[1]);
        MM(t_, B2, acc[2]);
      }
    }
    __builtin_amdgcn_sched_barrier(0);

    // epilogue: C/D map col=lane&15, row=(lane>>4)*4+reg (m89-verified).
    // Dual store: sc0 -> hbl (own XCD L2), sc0sc1 -> hbX (L3, for layer l+1).
    short* hout = hb + (size_t)par * HSLOT + (size_t)l * HLAY;
    short* houtL = hbl + (size_t)par * HLPAR + (size_t)gi * 131072;
#pragma unroll
    for (int rr = 0; rr < 4; ++rr) {
      int mloc = w * 16 + kgrp * 4 + rr;   // local row 0..255
      int rowg = R0 + mloc;
      int bb = rowg >> 6, aa = rowg & 63;
      size_t vofs = ((size_t)bb * Tc + t) * 64 + aa;
      int vld = valid[vofs];
      float ir = acc[0][rr] + bi0;
      float iz = acc[1][rr] + bi1;
      float in_ = acc[2][rr] + bi2;
      float hr = acc[3][rr] + bh0;
      float hz = acc[4][rr] + bh1;
      float hn = acc[5][rr] + bh2;
      float rg = 1.0f / (1.0f + __expf(-(ir + hr)));
      float zg = 1.0f / (1.0f + __expf(-(iz + hz)));
      float ng = tanhf(in_ + rg * hn);
      float hnew = (1.0f - zg) * ng + zg * hreg[rr];
      if (!vld) hnew = 0.0f;
      hreg[rr] = hnew;
      int hv = (int)f2bf(hnew);
      STORE_HL(houtL + (size_t)mloc * Hc + c, hv);
      if (l < 2) STORE_H2(hout + (size_t)rowg * Hc + c, hv);
      else       y[vofs * Hc + c] = hnew;   // l=2: only y consumer
    }

    asm volatile("s_waitcnt vmcnt(0)" ::: "memory");   // all stores retired
    __syncthreads();                                   // all waves' stores done
    if (tid == 0) {                  // publish: single sc STORE, no RMW
      int v = t + 1;
      STORE_D(done + gi * 32 + cb, v);
    }
    WAITV(0);   // drain publish store: vmcnt clean for next counted region
  }
}

extern "C" void kernel_launch(void* const* d_in, const int* in_sizes, int n_in,
                              void* d_out, int out_size, void* d_ws, size_t ws_size,
                              hipStream_t stream) {
  const float* x = (const float*)d_in[0];
  const int* valid = (const int*)d_in[1];
  const float* w_ih = (const float*)d_in[2];
  const float* w_hh = (const float*)d_in[3];
  const float* b_ih = (const float*)d_in[4];
  const float* b_hh = (const float*)d_in[5];
  float* y = (float*)d_out;

  char* ws = (char*)d_ws;
  const size_t welems = (size_t)Lc * H3c * Hc;            // 2,359,296
  unsigned short* wbih = (unsigned short*)ws;
  unsigned short* wbhh = (unsigned short*)(ws + welems * 2);
  short* hb = (short*)(ws + welems * 4);                  // 3.0 MB L3 ring
  const size_t hb_bytes = (size_t)2 * HSLOT * 2;
  int* done = (int*)(ws + welems * 4 + hb_bytes);         // [6][32] = 768 B
  const size_t flags_bytes = 4800;
  const size_t hbl_off = welems * 4 + hb_bytes + flags_bytes;
  const size_t hbl_bytes = (size_t)2 * HLPAR * 2;         // 3.0 MB local ring
  short* hbl = (short*)(ws + hbl_off);
  const size_t xb_off = hbl_off + hbl_bytes;              // 16B aligned
  const size_t xelems = (size_t)8 * Tc * 64 * Hc;         // 26,214,400
  const bool big = ws_size >= xb_off + xelems * 2;
  unsigned short* xbf = big ? (unsigned short*)(ws + xb_off) : nullptr;

  int n4w = (int)(welems / 4);
  conv_bf16<<<(n4w + 255) / 256, 256, 0, stream>>>(w_ih, wbih, n4w);
  conv_bf16<<<(n4w + 255) / 256, 256, 0, stream>>>(w_hh, wbhh, n4w);
  if (big) {
    int n4x = (int)(xelems / 4);
    conv_bf16<<<(n4x + 255) / 256, 256, 0, stream>>>(x, xbf, n4x);
  }
  (void)hipMemsetAsync(hb, 0, hb_bytes + flags_bytes, stream);  // hbl needs no init

  gru_persist14<<<256, 1024, 0, stream>>>(x, (const short*)xbf,
                                          (const short*)wbih, (const short*)wbhh,
                                          b_ih, b_hh, hb, hbl, valid, y, done);
}